// Round 4
// baseline (1148.824 us; speedup 1.0000x reference)
//
#include <hip/hip_runtime.h>

#define NNODES 50000
#define NEDGES 800000

typedef unsigned short ushort_t;

__device__ __forceinline__ float bf2f(unsigned short u) {
  union { unsigned int i; float f; } v; v.i = ((unsigned int)u) << 16; return v.f;
}
__device__ __forceinline__ unsigned short f2bf(float f) {
  union { float f; unsigned int i; } v; v.f = f;
  unsigned int r = v.i + 0x7fffu + ((v.i >> 16) & 1u);
  return (unsigned short)(r >> 16);
}

// ---------------- graph preprocessing ----------------

__global__ void hist_kernel(const int* dst, int* cnt) {
  int i = blockIdx.x * 256 + threadIdx.x;
  if (i < NEDGES) atomicAdd(&cnt[dst[i]], 1);
}

__global__ void dinv_kernel(const int* cnt, float* dinv) {
  int i = blockIdx.x * 256 + threadIdx.x;
  if (i < NNODES) dinv[i] = rsqrtf((float)(cnt[i] + 1));  // +1 self loop
}

__global__ void scan_kernel(const int* cnt, int* row_ptr, int* cursor) {
  __shared__ int sums[256];
  int t = threadIdx.x;
  const int STRIP = (NNODES + 255) / 256;
  int s0 = t * STRIP; if (s0 > NNODES) s0 = NNODES;
  int s1 = s0 + STRIP; if (s1 > NNODES) s1 = NNODES;
  int sum = 0;
  for (int i = s0; i < s1; ++i) sum += cnt[i];
  sums[t] = sum;
  __syncthreads();
  for (int off = 1; off < 256; off <<= 1) {
    int x = (t >= off) ? sums[t - off] : 0;
    __syncthreads();
    sums[t] += x;
    __syncthreads();
  }
  int run = sums[t] - sum;  // exclusive prefix of this strip
  for (int i = s0; i < s1; ++i) {
    row_ptr[i] = run; cursor[i] = run; run += cnt[i];
  }
  if (t == 255) row_ptr[NNODES] = run;
}

__global__ void fill_kernel(const int* src, const int* dst, int* cursor, int* col_idx) {
  int i = blockIdx.x * 256 + threadIdx.x;
  if (i < NEDGES) {
    int p = atomicAdd(&cursor[dst[i]], 1);
    col_idx[p] = src[i];
  }
}

// ---------------- f32 -> bf16 conversion (x only) ----------------
__global__ void cvt_kernel(const float* in, ushort_t* out, int n4) {
  int i = blockIdx.x * 256 + threadIdx.x;
  if (i < n4) {
    float4 v = *(const float4*)(in + (size_t)i * 4);
    uint2 o;
    o.x = (unsigned int)f2bf(v.x) | ((unsigned int)f2bf(v.y) << 16);
    o.y = (unsigned int)f2bf(v.z) | ((unsigned int)f2bf(v.w) << 16);
    *(uint2*)(out + (size_t)i * 4) = o;
  }
}

// ---------------- aggregation (CSR, one wave per node, bf16 act) ----------
// out[i] = act( dinv[i]*(dinv[i]*in[i] + sum_j dinv[j]*in[j]) + bias )
// mode 0: plain; 1: +bias leaky_relu(0.01)

template <int WPL>
__device__ __forceinline__ void load_row(const ushort_t* p, float* f) {
  if (WPL == 2) {
    unsigned int u = *(const unsigned int*)p;
    f[0] = bf2f((unsigned short)(u & 0xffff));
    f[1] = bf2f((unsigned short)(u >> 16));
  } else {
    uint2 u = *(const uint2*)p;
    f[0] = bf2f((unsigned short)(u.x & 0xffff));
    f[1] = bf2f((unsigned short)(u.x >> 16));
    f[2] = bf2f((unsigned short)(u.y & 0xffff));
    f[3] = bf2f((unsigned short)(u.y >> 16));
  }
}

template <int WPL>
__global__ __launch_bounds__(256) void agg_kernel(
    const ushort_t* in, ushort_t* out, const int* row_ptr, const int* col_idx,
    const float* dinv, const float* bias, int mode) {
  const int W = WPL * 64;
  int wid = blockIdx.x * 4 + (threadIdx.x >> 6);
  int lane = threadIdx.x & 63;
  int co = lane * WPL;
  float di = dinv[wid];
  float acc[WPL];
  {
    float v[WPL];
    load_row<WPL>(in + (size_t)wid * W + co, v);
#pragma unroll
    for (int c = 0; c < WPL; ++c) acc[c] = di * v[c];
  }
  int e0 = row_ptr[wid], e1 = row_ptr[wid + 1];
  for (int e = e0; e < e1; ++e) {
    int j = col_idx[e];
    float dj = dinv[j];
    float v[WPL];
    load_row<WPL>(in + (size_t)j * W + co, v);
#pragma unroll
    for (int c = 0; c < WPL; ++c) acc[c] += dj * v[c];
  }
  unsigned short o[WPL];
#pragma unroll
  for (int c = 0; c < WPL; ++c) {
    float v = acc[c] * di;
    if (mode) {
      v += bias[co + c];
      v = v > 0.f ? v : 0.01f * v;
    }
    o[c] = f2bf(v);
  }
  if (WPL == 2) {
    *(unsigned int*)(out + (size_t)wid * W + co) =
        (unsigned int)o[0] | ((unsigned int)o[1] << 16);
  } else {
    uint2 u;
    u.x = (unsigned int)o[0] | ((unsigned int)o[1] << 16);
    u.y = (unsigned int)o[2] | ((unsigned int)o[3] << 16);
    *(uint2*)(out + (size_t)wid * W + co) = u;
  }
}

// ---------------- GEMM (f32 VALU): C[M,N] = A[M,K] @ W[K,N] ----------------
// A is bf16 [M,K]; W, bias are f32; out bf16 or f32.
// 64x64 tile, BK=16, 256 threads, 4x4 per thread, f32 accumulate.
// mode 0: raw; 1: +bias leaky_relu(0.01); 2: +bias relu
#define TBM 64
#define TBN 64
#define TBK 16

__global__ __launch_bounds__(256) void gemm_kernel(
    const ushort_t* A, const float* Wm, void* Cv, const float* bias,
    int M, int K, int N, int mode, int out_f32) {
  __shared__ float As[TBK][TBM + 4];  // transposed: As[k][m]
  __shared__ float Ws[TBK][TBN + 4];
  int tid = threadIdx.x;
  int tx = tid & 15, ty = tid >> 4;
  int m0 = blockIdx.x * TBM, n0 = blockIdx.y * TBN;
  float acc[4][4];
#pragma unroll
  for (int i = 0; i < 4; ++i)
#pragma unroll
    for (int j = 0; j < 4; ++j) acc[i][j] = 0.f;

  for (int kb = 0; kb < K; kb += TBK) {
    // A tile: 64 rows x 16 k. thread t: row=t>>2, k4=(t&3)*4, 4 bf16 = uint2
    {
      int r = tid >> 2, k4 = (tid & 3) * 4;
      int gr = m0 + r; if (gr > M - 1) gr = M - 1;
      uint2 u = *(const uint2*)(A + (size_t)gr * K + kb + k4);
      As[k4 + 0][r] = bf2f((unsigned short)(u.x & 0xffff));
      As[k4 + 1][r] = bf2f((unsigned short)(u.x >> 16));
      As[k4 + 2][r] = bf2f((unsigned short)(u.y & 0xffff));
      As[k4 + 3][r] = bf2f((unsigned short)(u.y >> 16));
    }
    // W tile: 16 k x 64 n. thread t: k=t>>4, n4=(t&15)*4, float4
    {
      int r = tid >> 4, n4 = (tid & 15) * 4;
      float4 v = *(const float4*)(Wm + (size_t)(kb + r) * N + n0 + n4);
      *(float4*)&Ws[r][n4] = v;
    }
    __syncthreads();
#pragma unroll
    for (int k = 0; k < TBK; ++k) {
      float4 a4 = *(const float4*)&As[k][ty * 4];
      float4 b4 = *(const float4*)&Ws[k][tx * 4];
      float a[4] = {a4.x, a4.y, a4.z, a4.w};
      float b[4] = {b4.x, b4.y, b4.z, b4.w};
#pragma unroll
      for (int i = 0; i < 4; ++i)
#pragma unroll
        for (int j = 0; j < 4; ++j) acc[i][j] += a[i] * b[j];
    }
    __syncthreads();
  }

#pragma unroll
  for (int i = 0; i < 4; ++i) {
    int row = m0 + ty * 4 + i;
    if (row >= M) continue;
    int col = n0 + tx * 4;
    float v[4];
#pragma unroll
    for (int j = 0; j < 4; ++j) {
      v[j] = acc[i][j];
      if (mode) {
        v[j] += bias[col + j];
        v[j] = (mode == 1) ? (v[j] > 0.f ? v[j] : 0.01f * v[j])
                           : (v[j] > 0.f ? v[j] : 0.f);
      }
    }
    if (out_f32) {
      float4 o = {v[0], v[1], v[2], v[3]};
      *(float4*)((float*)Cv + (size_t)row * N + col) = o;
    } else {
      uint2 o;
      o.x = (unsigned int)f2bf(v[0]) | ((unsigned int)f2bf(v[1]) << 16);
      o.y = (unsigned int)f2bf(v[2]) | ((unsigned int)f2bf(v[3]) << 16);
      *(uint2*)((ushort_t*)Cv + (size_t)row * N + col) = o;
    }
  }
}

// ---------------- driver ----------------

extern "C" void kernel_launch(void* const* d_in, const int* in_sizes, int n_in,
                              void* d_out, int out_size, void* d_ws, size_t ws_size,
                              hipStream_t stream) {
  const float* x  = (const float*)d_in[0];
  const int* ei   = (const int*)d_in[1];
  const float* W1 = (const float*)d_in[2];
  const float* b1 = (const float*)d_in[3];
  const float* W2 = (const float*)d_in[4];
  const float* b2 = (const float*)d_in[5];
  const float* W3 = (const float*)d_in[6];
  const float* b3 = (const float*)d_in[7];
  const float* W4 = (const float*)d_in[8];
  const float* b4 = (const float*)d_in[9];
  const float* Wl = (const float*)d_in[10];
  const float* bl = (const float*)d_in[11];

  char* p = (char*)d_ws;
  auto alloc = [&](size_t bytes) {
    char* r = p;
    p += (bytes + 255) & ~(size_t)255;
    return r;
  };
  int* cnt      = (int*)alloc((size_t)NNODES * 4);
  int* cursor   = (int*)alloc((size_t)NNODES * 4);
  int* row_ptr  = (int*)alloc((size_t)(NNODES + 1) * 4);
  float* dinv   = (float*)alloc((size_t)NNODES * 4);
  int* col_idx  = (int*)alloc((size_t)NEDGES * 4);
  ushort_t* actA = (ushort_t*)alloc((size_t)NNODES * 384 * 2);
  ushort_t* actB = (ushort_t*)alloc((size_t)NNODES * 384 * 2);

  const int* src = ei;
  const int* dst = ei + NEDGES;

  hipMemsetAsync(cnt, 0, (size_t)NNODES * 4, stream);
  hist_kernel<<<(NEDGES + 255) / 256, 256, 0, stream>>>(dst, cnt);
  scan_kernel<<<1, 256, 0, stream>>>(cnt, row_ptr, cursor);
  dinv_kernel<<<(NNODES + 255) / 256, 256, 0, stream>>>(cnt, dinv);
  fill_kernel<<<(NEDGES + 255) / 256, 256, 0, stream>>>(src, dst, cursor, col_idx);

  dim3 blk(256);
  int gm = (NNODES + TBM - 1) / TBM;  // 782
  int nagg = NNODES / 4;              // 12500 blocks, wave per node

  // x (f32) -> bf16 in actB
  cvt_kernel<<<(NNODES * 384 / 4 + 255) / 256, 256, 0, stream>>>(x, actB, NNODES * 384 / 4);

  // L1 (384->128): multiply first, then agg(+b1, leaky)
  gemm_kernel<<<dim3(gm, 2), blk, 0, stream>>>(actB, W1, actA, (const float*)0, NNODES, 384, 128, 0, 0);
  agg_kernel<2><<<nagg, blk, 0, stream>>>(actA, actB, row_ptr, col_idx, dinv, b1, 1);
  // L2 (128->384): agg first (plain), then gemm(+b2, leaky)
  agg_kernel<2><<<nagg, blk, 0, stream>>>(actB, actA, row_ptr, col_idx, dinv, (const float*)0, 0);
  gemm_kernel<<<dim3(gm, 6), blk, 0, stream>>>(actA, W2, actB, b2, NNODES, 128, 384, 1, 0);
  // L3 (384->256): multiply first, then agg(+b3, leaky)
  gemm_kernel<<<dim3(gm, 4), blk, 0, stream>>>(actB, W3, actA, (const float*)0, NNODES, 384, 256, 0, 0);
  agg_kernel<4><<<nagg, blk, 0, stream>>>(actA, actB, row_ptr, col_idx, dinv, b3, 1);
  // L4 (256->384): agg first (plain), then gemm(+b4, leaky)
  agg_kernel<4><<<nagg, blk, 0, stream>>>(actB, actA, row_ptr, col_idx, dinv, (const float*)0, 0);
  gemm_kernel<<<dim3(gm, 6), blk, 0, stream>>>(actA, W4, actB, b4, NNODES, 256, 384, 1, 0);
  // final linear (384->128) + relu -> d_out (f32)
  gemm_kernel<<<dim3(gm, 2), blk, 0, stream>>>(actB, Wl, d_out, bl, NNODES, 384, 128, 2, 1);
}

// Round 5
// 932.039 us; speedup vs baseline: 1.2326x; 1.2326x over previous
//
#include <hip/hip_runtime.h>

#define NNODES 50000
#define NEDGES 800000

typedef unsigned short ushort_t;
typedef __attribute__((ext_vector_type(8))) short short8;
typedef __attribute__((ext_vector_type(4))) float floatx4;

__device__ __forceinline__ float bf2f(unsigned short u) {
  union { unsigned int i; float f; } v; v.i = ((unsigned int)u) << 16; return v.f;
}
__device__ __forceinline__ unsigned short f2bf(float f) {
  union { float f; unsigned int i; } v; v.f = f;
  unsigned int r = v.i + 0x7fffu + ((v.i >> 16) & 1u);
  return (unsigned short)(r >> 16);
}

// ---------------- graph preprocessing ----------------

__global__ void hist_kernel(const int* dst, int* cnt) {
  int i = blockIdx.x * 256 + threadIdx.x;
  if (i < NEDGES) atomicAdd(&cnt[dst[i]], 1);
}

__global__ void dinv_kernel(const int* cnt, float* dinv) {
  int i = blockIdx.x * 256 + threadIdx.x;
  if (i < NNODES) dinv[i] = rsqrtf((float)(cnt[i] + 1));  // +1 self loop
}

__global__ void scan_kernel(const int* cnt, int* row_ptr, int* cursor) {
  __shared__ int sums[256];
  int t = threadIdx.x;
  const int STRIP = (NNODES + 255) / 256;
  int s0 = t * STRIP; if (s0 > NNODES) s0 = NNODES;
  int s1 = s0 + STRIP; if (s1 > NNODES) s1 = NNODES;
  int sum = 0;
  for (int i = s0; i < s1; ++i) sum += cnt[i];
  sums[t] = sum;
  __syncthreads();
  for (int off = 1; off < 256; off <<= 1) {
    int x = (t >= off) ? sums[t - off] : 0;
    __syncthreads();
    sums[t] += x;
    __syncthreads();
  }
  int run = sums[t] - sum;  // exclusive prefix of this strip
  for (int i = s0; i < s1; ++i) {
    row_ptr[i] = run; cursor[i] = run; run += cnt[i];
  }
  if (t == 255) row_ptr[NNODES] = run;
}

__global__ void fill_kernel(const int* src, const int* dst, int* cursor, int* col_idx) {
  int i = blockIdx.x * 256 + threadIdx.x;
  if (i < NEDGES) {
    int p = atomicAdd(&cursor[dst[i]], 1);
    col_idx[p] = src[i];
  }
}

// ---------------- f32 -> bf16 conversion (x only) ----------------
__global__ void cvt_kernel(const float* in, ushort_t* out, int n4) {
  int i = blockIdx.x * 256 + threadIdx.x;
  if (i < n4) {
    float4 v = *(const float4*)(in + (size_t)i * 4);
    uint2 o;
    o.x = (unsigned int)f2bf(v.x) | ((unsigned int)f2bf(v.y) << 16);
    o.y = (unsigned int)f2bf(v.z) | ((unsigned int)f2bf(v.w) << 16);
    *(uint2*)(out + (size_t)i * 4) = o;
  }
}

// ---------------- weight prep: transpose + split into bf16 hi/lo ----------
// hi[n*K+k] = bf16(W[k][n]);  lo = bf16(W[k][n] - hi)
__global__ void wprep_kernel(const float* W, ushort_t* hi, ushort_t* lo, int K, int N) {
  int idx = blockIdx.x * 256 + threadIdx.x;
  if (idx < K * N) {
    int n = idx / K, k = idx - n * K;
    float w = W[(size_t)k * N + n];
    unsigned short h = f2bf(w);
    hi[idx] = h;
    lo[idx] = f2bf(w - bf2f(h));
  }
}

// ---------------- aggregation (CSR, one wave per node, bf16 act) ----------
// Inputs are PRE-SCALED by source dinv:  s[j] = dinv[j] * h[j].
// out[i] = store( act( dinv[i] * sum_{j in {i} u N(i)} s[j] + bias ) [* dinv[i]] )
// mode 0: plain (no bias/act); 1: +bias leaky_relu(0.01)

template <int WPL>
__device__ __forceinline__ void load_row(const ushort_t* p, float* f) {
  if (WPL == 2) {
    unsigned int u = *(const unsigned int*)p;
    f[0] = bf2f((unsigned short)(u & 0xffff));
    f[1] = bf2f((unsigned short)(u >> 16));
  } else {
    uint2 u = *(const uint2*)p;
    f[0] = bf2f((unsigned short)(u.x & 0xffff));
    f[1] = bf2f((unsigned short)(u.x >> 16));
    f[2] = bf2f((unsigned short)(u.y & 0xffff));
    f[3] = bf2f((unsigned short)(u.y >> 16));
  }
}

template <int WPL>
__global__ __launch_bounds__(256) void agg_kernel(
    const ushort_t* __restrict__ in, ushort_t* __restrict__ out,
    const int* __restrict__ row_ptr, const int* __restrict__ col_idx,
    const float* __restrict__ dinv, const float* __restrict__ bias,
    int mode, int scale_store) {
  const int W = WPL * 64;
  int wid = blockIdx.x * 4 + (threadIdx.x >> 6);
  int lane = threadIdx.x & 63;
  int co = lane * WPL;
  const ushort_t* base = in + co;
  float acc[WPL];
  {
    float v[WPL];
    load_row<WPL>(base + (size_t)wid * W, v);
#pragma unroll
    for (int c = 0; c < WPL; ++c) acc[c] = v[c];
  }
  int e = row_ptr[wid], e1 = row_ptr[wid + 1];
  for (; e + 4 <= e1; e += 4) {
    int j0 = col_idx[e], j1 = col_idx[e + 1], j2 = col_idx[e + 2], j3 = col_idx[e + 3];
    float v0[WPL], v1[WPL], v2[WPL], v3[WPL];
    load_row<WPL>(base + (size_t)j0 * W, v0);
    load_row<WPL>(base + (size_t)j1 * W, v1);
    load_row<WPL>(base + (size_t)j2 * W, v2);
    load_row<WPL>(base + (size_t)j3 * W, v3);
#pragma unroll
    for (int c = 0; c < WPL; ++c) acc[c] += (v0[c] + v1[c]) + (v2[c] + v3[c]);
  }
  for (; e < e1; ++e) {
    int j = col_idx[e];
    float v[WPL];
    load_row<WPL>(base + (size_t)j * W, v);
#pragma unroll
    for (int c = 0; c < WPL; ++c) acc[c] += v[c];
  }
  float di = dinv[wid];
  unsigned short o[WPL];
  if (mode) {
    float bb[WPL];
    if constexpr (WPL == 2) {
      float2 b2 = *(const float2*)(bias + co); bb[0] = b2.x; bb[1] = b2.y;
    } else {
      float4 b4 = *(const float4*)(bias + co);
      bb[0] = b4.x; bb[1] = b4.y; bb[2] = b4.z; bb[3] = b4.w;
    }
    float sc = scale_store ? di : 1.f;
#pragma unroll
    for (int c = 0; c < WPL; ++c) {
      float v = acc[c] * di + bb[c];
      v = v > 0.f ? v : 0.01f * v;
      o[c] = f2bf(v * sc);
    }
  } else {
#pragma unroll
    for (int c = 0; c < WPL; ++c) o[c] = f2bf(acc[c] * di);
  }
  if constexpr (WPL == 2) {
    *(unsigned int*)(out + (size_t)wid * W + co) =
        (unsigned int)o[0] | ((unsigned int)o[1] << 16);
  } else {
    uint2 u;
    u.x = (unsigned int)o[0] | ((unsigned int)o[1] << 16);
    u.y = (unsigned int)o[2] | ((unsigned int)o[3] << 16);
    *(uint2*)(out + (size_t)wid * W + co) = u;
  }
}

// ---------------- MFMA GEMM: C = A[M,K] @ (Bhi+Blo)[N,K]^T ----------------
// A bf16 row-major; Bhi/Blo bf16 [N,K] (pre-transposed split weights).
// 128x128 tile, BK=32, 4 waves (2x2), 4x4 16x16x32 fragments, 2 MFMA per
// fragment pair (hi+lo). mode 0: raw; 1: +bias leaky; 2: +bias relu.
// scale_store: multiply final value by dinv[row]. out_f32: f32 store else bf16.

#define BM 128
#define BN 128
#define BK 32

__global__ __launch_bounds__(256, 2) void gemm_mfma(
    const ushort_t* __restrict__ A, const ushort_t* __restrict__ Bhi,
    const ushort_t* __restrict__ Blo, void* __restrict__ Cv,
    const float* __restrict__ bias, const float* __restrict__ dinv,
    int M, int K, int ldc, int mode, int scale_store, int out_f32) {
  __shared__ ushort_t As[BM * BK];
  __shared__ ushort_t Bh[BN * BK];
  __shared__ ushort_t Bl[BN * BK];
  int tid = threadIdx.x;
  int lane = tid & 63, w = tid >> 6;
  int wm = w & 1, wn = w >> 1;
  int m0 = blockIdx.x * BM, n0 = blockIdx.y * BN;
  floatx4 acc[4][4] = {};
  int nkt = K / BK;
  for (int kt = 0; kt < nkt; ++kt) {
    int kb = kt * BK;
    uint4 va[2], vh[2], vl[2];
#pragma unroll
    for (int it = 0; it < 2; ++it) {
      int s = it * 256 + tid;
      int row = s >> 2, ks = (s & 3) * 8;
      int gr = m0 + row; if (gr > M - 1) gr = M - 1;  // clamp loads; stores guarded
      va[it] = *(const uint4*)(A + (size_t)gr * K + kb + ks);
      vh[it] = *(const uint4*)(Bhi + (size_t)(n0 + row) * K + kb + ks);
      vl[it] = *(const uint4*)(Blo + (size_t)(n0 + row) * K + kb + ks);
    }
    __syncthreads();  // previous iteration's LDS reads complete
#pragma unroll
    for (int it = 0; it < 2; ++it) {
      int s = it * 256 + tid;
      int row = s >> 2, ks = (s & 3) * 8;
      *(uint4*)&As[row * BK + ks] = va[it];
      *(uint4*)&Bh[row * BK + ks] = vh[it];
      *(uint4*)&Bl[row * BK + ks] = vl[it];
    }
    __syncthreads();
    short8 af[4], fh[4], fl[4];
#pragma unroll
    for (int f = 0; f < 4; ++f)
      af[f] = *(const short8*)&As[(wm * 64 + f * 16 + (lane & 15)) * BK + (lane >> 4) * 8];
#pragma unroll
    for (int g = 0; g < 4; ++g) {
      int o = (wn * 64 + g * 16 + (lane & 15)) * BK + (lane >> 4) * 8;
      fh[g] = *(const short8*)&Bh[o];
      fl[g] = *(const short8*)&Bl[o];
    }
#pragma unroll
    for (int f = 0; f < 4; ++f)
#pragma unroll
      for (int g = 0; g < 4; ++g) {
        acc[f][g] = __builtin_amdgcn_mfma_f32_16x16x32_bf16(af[f], fh[g], acc[f][g], 0, 0, 0);
        acc[f][g] = __builtin_amdgcn_mfma_f32_16x16x32_bf16(af[f], fl[g], acc[f][g], 0, 0, 0);
      }
  }
  int cr = lane >> 4, cc = lane & 15;
#pragma unroll
  for (int f = 0; f < 4; ++f) {
#pragma unroll
    for (int r = 0; r < 4; ++r) {
      int row = m0 + wm * 64 + f * 16 + cr * 4 + r;
      if (row >= M) continue;
      float sc = scale_store ? dinv[row] : 1.f;
#pragma unroll
      for (int g = 0; g < 4; ++g) {
        int col = n0 + wn * 64 + g * 16 + cc;
        float v = acc[f][g][r];
        if (mode) {
          v += bias[col];
          v = (mode == 1) ? (v > 0.f ? v : 0.01f * v) : (v > 0.f ? v : 0.f);
        }
        v *= sc;
        if (out_f32) ((float*)Cv)[(size_t)row * ldc + col] = v;
        else ((ushort_t*)Cv)[(size_t)row * ldc + col] = f2bf(v);
      }
    }
  }
}

// ---------------- driver ----------------

extern "C" void kernel_launch(void* const* d_in, const int* in_sizes, int n_in,
                              void* d_out, int out_size, void* d_ws, size_t ws_size,
                              hipStream_t stream) {
  const float* x  = (const float*)d_in[0];
  const int* ei   = (const int*)d_in[1];
  const float* W1 = (const float*)d_in[2];
  const float* b1 = (const float*)d_in[3];
  const float* W2 = (const float*)d_in[4];
  const float* b2 = (const float*)d_in[5];
  const float* W3 = (const float*)d_in[6];
  const float* b3 = (const float*)d_in[7];
  const float* W4 = (const float*)d_in[8];
  const float* b4 = (const float*)d_in[9];
  const float* Wl = (const float*)d_in[10];
  const float* bl = (const float*)d_in[11];

  char* p = (char*)d_ws;
  auto alloc = [&](size_t bytes) {
    char* r = p;
    p += (bytes + 255) & ~(size_t)255;
    return r;
  };
  int* cnt      = (int*)alloc((size_t)NNODES * 4);
  int* cursor   = (int*)alloc((size_t)NNODES * 4);
  int* row_ptr  = (int*)alloc((size_t)(NNODES + 1) * 4);
  float* dinv   = (float*)alloc((size_t)NNODES * 4);
  int* col_idx  = (int*)alloc((size_t)NEDGES * 4);
  ushort_t* W1h = (ushort_t*)alloc(49152 * 2); ushort_t* W1l = (ushort_t*)alloc(49152 * 2);
  ushort_t* W2h = (ushort_t*)alloc(49152 * 2); ushort_t* W2l = (ushort_t*)alloc(49152 * 2);
  ushort_t* W3h = (ushort_t*)alloc(98304 * 2); ushort_t* W3l = (ushort_t*)alloc(98304 * 2);
  ushort_t* W4h = (ushort_t*)alloc(98304 * 2); ushort_t* W4l = (ushort_t*)alloc(98304 * 2);
  ushort_t* Wlh = (ushort_t*)alloc(49152 * 2); ushort_t* Wll = (ushort_t*)alloc(49152 * 2);
  ushort_t* actA = (ushort_t*)alloc((size_t)NNODES * 384 * 2);
  ushort_t* actB = (ushort_t*)alloc((size_t)NNODES * 384 * 2);

  const int* src = ei;
  const int* dst = ei + NEDGES;

  hipMemsetAsync(cnt, 0, (size_t)NNODES * 4, stream);
  hist_kernel<<<(NEDGES + 255) / 256, 256, 0, stream>>>(dst, cnt);
  scan_kernel<<<1, 256, 0, stream>>>(cnt, row_ptr, cursor);
  dinv_kernel<<<(NNODES + 255) / 256, 256, 0, stream>>>(cnt, dinv);
  fill_kernel<<<(NEDGES + 255) / 256, 256, 0, stream>>>(src, dst, cursor, col_idx);

  wprep_kernel<<<(49152 + 255) / 256, 256, 0, stream>>>(W1, W1h, W1l, 384, 128);
  wprep_kernel<<<(49152 + 255) / 256, 256, 0, stream>>>(W2, W2h, W2l, 128, 384);
  wprep_kernel<<<(98304 + 255) / 256, 256, 0, stream>>>(W3, W3h, W3l, 384, 256);
  wprep_kernel<<<(98304 + 255) / 256, 256, 0, stream>>>(W4, W4h, W4l, 256, 384);
  wprep_kernel<<<(49152 + 255) / 256, 256, 0, stream>>>(Wl, Wlh, Wll, 384, 128);

  // x (f32) -> bf16 in actB
  cvt_kernel<<<(NNODES * 384 / 4 + 255) / 256, 256, 0, stream>>>(x, actB, NNODES * 384 / 4);

  dim3 blk(256);
  int gm = (NNODES + BM - 1) / BM;  // 391
  int nagg = NNODES / 4;            // 12500 blocks, one wave per node

  // L1 (384->128): gemm (pre-scaled store), agg(+b1, leaky, pre-scaled store)
  gemm_mfma<<<dim3(gm, 1), blk, 0, stream>>>(actB, W1h, W1l, actA, (const float*)0, dinv, NNODES, 384, 128, 0, 1, 0);
  agg_kernel<2><<<nagg, blk, 0, stream>>>(actA, actB, row_ptr, col_idx, dinv, b1, 1, 1);
  // L2 (128->384): agg (plain), gemm(+b2, leaky)
  agg_kernel<2><<<nagg, blk, 0, stream>>>(actB, actA, row_ptr, col_idx, dinv, (const float*)0, 0, 0);
  gemm_mfma<<<dim3(gm, 3), blk, 0, stream>>>(actA, W2h, W2l, actB, b2, dinv, NNODES, 128, 384, 1, 0, 0);
  // L3 (384->256): gemm (pre-scaled store), agg(+b3, leaky, pre-scaled store)
  gemm_mfma<<<dim3(gm, 2), blk, 0, stream>>>(actB, W3h, W3l, actA, (const float*)0, dinv, NNODES, 384, 256, 0, 1, 0);
  agg_kernel<4><<<nagg, blk, 0, stream>>>(actA, actB, row_ptr, col_idx, dinv, b3, 1, 1);
  // L4 (256->384): agg (plain), gemm(+b4, leaky)
  agg_kernel<4><<<nagg, blk, 0, stream>>>(actB, actA, row_ptr, col_idx, dinv, (const float*)0, 0, 0);
  gemm_mfma<<<dim3(gm, 3), blk, 0, stream>>>(actA, W4h, W4l, actB, b4, dinv, NNODES, 256, 384, 1, 0, 0);
  // final linear (384->128) + relu -> d_out (f32)
  gemm_mfma<<<dim3(gm, 1), blk, 0, stream>>>(actB, Wlh, Wll, d_out, bl, dinv, NNODES, 384, 128, 2, 0, 1);
}

// Round 6
// 799.283 us; speedup vs baseline: 1.4373x; 1.1661x over previous
//
#include <hip/hip_runtime.h>

#define NNODES 50000
#define NEDGES 800000
#define NTILES ((NNODES + 255) / 256)   // 196

typedef unsigned short ushort_t;
typedef __attribute__((ext_vector_type(8))) short short8;
typedef __attribute__((ext_vector_type(4))) float floatx4;

__device__ __forceinline__ float bf2f(unsigned short u) {
  union { unsigned int i; float f; } v; v.i = ((unsigned int)u) << 16; return v.f;
}
__device__ __forceinline__ unsigned short f2bf(float f) {
  union { float f; unsigned int i; } v; v.f = f;
  unsigned int r = v.i + 0x7fffu + ((v.i >> 16) & 1u);
  return (unsigned short)(r >> 16);
}

// ---------------- graph preprocessing ----------------

__global__ void hist_kernel(const int* dst, int* cnt) {
  int i = blockIdx.x * 256 + threadIdx.x;
  if (i < NEDGES) atomicAdd(&cnt[dst[i]], 1);
}

__global__ void dinv_kernel(const int* cnt, float* dinv) {
  int i = blockIdx.x * 256 + threadIdx.x;
  if (i < NNODES) dinv[i] = rsqrtf((float)(cnt[i] + 1));  // +1 self loop
}

// ---- device-wide exclusive scan of cnt[0..NNODES) in 3 tiny kernels ----

__global__ __launch_bounds__(256) void tile_scan_kernel(
    const int* __restrict__ cnt, int* __restrict__ tile_pref, int* __restrict__ tile_sum) {
  __shared__ int s[256];
  int b = blockIdx.x, t = threadIdx.x;
  int i = b * 256 + t;
  int v = (i < NNODES) ? cnt[i] : 0;
  s[t] = v;
  __syncthreads();
#pragma unroll
  for (int off = 1; off < 256; off <<= 1) {
    int x = (t >= off) ? s[t - off] : 0;
    __syncthreads();
    s[t] += x;
    __syncthreads();
  }
  if (i < NNODES) tile_pref[i] = s[t] - v;   // exclusive within tile
  if (t == 255) tile_sum[b] = s[255];
}

__global__ __launch_bounds__(256) void sum_scan_kernel(
    const int* __restrict__ tile_sum, int* __restrict__ tile_base) {
  __shared__ int s[256];
  int t = threadIdx.x;
  int v = (t < NTILES) ? tile_sum[t] : 0;
  s[t] = v;
  __syncthreads();
#pragma unroll
  for (int off = 1; off < 256; off <<= 1) {
    int x = (t >= off) ? s[t - off] : 0;
    __syncthreads();
    s[t] += x;
    __syncthreads();
  }
  if (t < NTILES) tile_base[t] = s[t] - v;   // exclusive across tiles
}

__global__ __launch_bounds__(256) void scan_write_kernel(
    const int* __restrict__ cnt, const int* __restrict__ tile_pref,
    const int* __restrict__ tile_base, int* __restrict__ row_ptr,
    int* __restrict__ cursor) {
  int b = blockIdx.x, t = threadIdx.x;
  int i = b * 256 + t;
  if (i < NNODES) {
    int base = tile_base[b] + tile_pref[i];
    row_ptr[i] = base;
    cursor[i] = base;
    if (i == NNODES - 1) row_ptr[NNODES] = base + cnt[i];
  }
}

__global__ void fill_kernel(const int* src, const int* dst, int* cursor, int* col_idx) {
  int i = blockIdx.x * 256 + threadIdx.x;
  if (i < NEDGES) {
    int p = atomicAdd(&cursor[dst[i]], 1);
    col_idx[p] = src[i];
  }
}

// ---------------- f32 -> bf16 conversion (x only) ----------------
__global__ void cvt_kernel(const float* in, ushort_t* out, int n4) {
  int i = blockIdx.x * 256 + threadIdx.x;
  if (i < n4) {
    float4 v = *(const float4*)(in + (size_t)i * 4);
    uint2 o;
    o.x = (unsigned int)f2bf(v.x) | ((unsigned int)f2bf(v.y) << 16);
    o.y = (unsigned int)f2bf(v.z) | ((unsigned int)f2bf(v.w) << 16);
    *(uint2*)(out + (size_t)i * 4) = o;
  }
}

// ---------------- weight prep: transpose + split into bf16 hi/lo ----------
__global__ void wprep_kernel(const float* W, ushort_t* hi, ushort_t* lo, int K, int N) {
  int idx = blockIdx.x * 256 + threadIdx.x;
  if (idx < K * N) {
    int n = idx / K, k = idx - n * K;
    float w = W[(size_t)k * N + n];
    unsigned short h = f2bf(w);
    hi[idx] = h;
    lo[idx] = f2bf(w - bf2f(h));
  }
}

// ---------------- aggregation (CSR, one wave per node, bf16 act) ----------
// Inputs PRE-SCALED by source dinv. out[i] = act(dinv[i]*sum + bias)[*dinv[i]]
// mode 0: plain; 1: +bias leaky_relu(0.01)

template <int WPL>
__device__ __forceinline__ void load_row(const ushort_t* p, float* f) {
  if (WPL == 2) {
    unsigned int u = *(const unsigned int*)p;
    f[0] = bf2f((unsigned short)(u & 0xffff));
    f[1] = bf2f((unsigned short)(u >> 16));
  } else {
    uint2 u = *(const uint2*)p;
    f[0] = bf2f((unsigned short)(u.x & 0xffff));
    f[1] = bf2f((unsigned short)(u.x >> 16));
    f[2] = bf2f((unsigned short)(u.y & 0xffff));
    f[3] = bf2f((unsigned short)(u.y >> 16));
  }
}

template <int WPL>
__global__ __launch_bounds__(256) void agg_kernel(
    const ushort_t* __restrict__ in, ushort_t* __restrict__ out,
    const int* __restrict__ row_ptr, const int* __restrict__ col_idx,
    const float* __restrict__ dinv, const float* __restrict__ bias,
    int mode, int scale_store) {
  const int W = WPL * 64;
  int wid = blockIdx.x * 4 + (threadIdx.x >> 6);
  int lane = threadIdx.x & 63;
  int co = lane * WPL;
  const ushort_t* base = in + co;
  float acc[WPL];
  {
    float v[WPL];
    load_row<WPL>(base + (size_t)wid * W, v);
#pragma unroll
    for (int c = 0; c < WPL; ++c) acc[c] = v[c];
  }
  int e = row_ptr[wid], e1 = row_ptr[wid + 1];
  for (; e + 8 <= e1; e += 8) {
    int j[8];
#pragma unroll
    for (int q = 0; q < 8; ++q) j[q] = col_idx[e + q];
    float v[8][WPL];
#pragma unroll
    for (int q = 0; q < 8; ++q) load_row<WPL>(base + (size_t)j[q] * W, v[q]);
#pragma unroll
    for (int c = 0; c < WPL; ++c)
      acc[c] += ((v[0][c] + v[1][c]) + (v[2][c] + v[3][c])) +
                ((v[4][c] + v[5][c]) + (v[6][c] + v[7][c]));
  }
  for (; e + 2 <= e1; e += 2) {
    int j0 = col_idx[e], j1 = col_idx[e + 1];
    float v0[WPL], v1[WPL];
    load_row<WPL>(base + (size_t)j0 * W, v0);
    load_row<WPL>(base + (size_t)j1 * W, v1);
#pragma unroll
    for (int c = 0; c < WPL; ++c) acc[c] += v0[c] + v1[c];
  }
  if (e < e1) {
    int j = col_idx[e];
    float v[WPL];
    load_row<WPL>(base + (size_t)j * W, v);
#pragma unroll
    for (int c = 0; c < WPL; ++c) acc[c] += v[c];
  }
  float di = dinv[wid];
  unsigned short o[WPL];
  if (mode) {
    float bb[WPL];
    if constexpr (WPL == 2) {
      float2 b2 = *(const float2*)(bias + co); bb[0] = b2.x; bb[1] = b2.y;
    } else {
      float4 b4 = *(const float4*)(bias + co);
      bb[0] = b4.x; bb[1] = b4.y; bb[2] = b4.z; bb[3] = b4.w;
    }
    float sc = scale_store ? di : 1.f;
#pragma unroll
    for (int c = 0; c < WPL; ++c) {
      float v = acc[c] * di + bb[c];
      v = v > 0.f ? v : 0.01f * v;
      o[c] = f2bf(v * sc);
    }
  } else {
#pragma unroll
    for (int c = 0; c < WPL; ++c) o[c] = f2bf(acc[c] * di);
  }
  if constexpr (WPL == 2) {
    *(unsigned int*)(out + (size_t)wid * W + co) =
        (unsigned int)o[0] | ((unsigned int)o[1] << 16);
  } else {
    uint2 u;
    u.x = (unsigned int)o[0] | ((unsigned int)o[1] << 16);
    u.y = (unsigned int)o[2] | ((unsigned int)o[3] << 16);
    *(uint2*)(out + (size_t)wid * W + co) = u;
  }
}

// ---------------- MFMA GEMM: C = A[M,K] @ (Bhi+Blo)[N,K]^T ----------------

#define BM 128
#define BN 128
#define BK 32

__global__ __launch_bounds__(256, 2) void gemm_mfma(
    const ushort_t* __restrict__ A, const ushort_t* __restrict__ Bhi,
    const ushort_t* __restrict__ Blo, void* __restrict__ Cv,
    const float* __restrict__ bias, const float* __restrict__ dinv,
    int M, int K, int ldc, int mode, int scale_store, int out_f32) {
  __shared__ ushort_t As[BM * BK];
  __shared__ ushort_t Bh[BN * BK];
  __shared__ ushort_t Bl[BN * BK];
  int tid = threadIdx.x;
  int lane = tid & 63, w = tid >> 6;
  int wm = w & 1, wn = w >> 1;
  int m0 = blockIdx.x * BM, n0 = blockIdx.y * BN;
  floatx4 acc[4][4] = {};
  int nkt = K / BK;
  for (int kt = 0; kt < nkt; ++kt) {
    int kb = kt * BK;
    uint4 va[2], vh[2], vl[2];
#pragma unroll
    for (int it = 0; it < 2; ++it) {
      int s = it * 256 + tid;
      int row = s >> 2, ks = (s & 3) * 8;
      int gr = m0 + row; if (gr > M - 1) gr = M - 1;  // clamp loads; stores guarded
      va[it] = *(const uint4*)(A + (size_t)gr * K + kb + ks);
      vh[it] = *(const uint4*)(Bhi + (size_t)(n0 + row) * K + kb + ks);
      vl[it] = *(const uint4*)(Blo + (size_t)(n0 + row) * K + kb + ks);
    }
    __syncthreads();  // previous iteration's LDS reads complete
#pragma unroll
    for (int it = 0; it < 2; ++it) {
      int s = it * 256 + tid;
      int row = s >> 2, ks = (s & 3) * 8;
      *(uint4*)&As[row * BK + ks] = va[it];
      *(uint4*)&Bh[row * BK + ks] = vh[it];
      *(uint4*)&Bl[row * BK + ks] = vl[it];
    }
    __syncthreads();
    short8 af[4], fh[4], fl[4];
#pragma unroll
    for (int f = 0; f < 4; ++f)
      af[f] = *(const short8*)&As[(wm * 64 + f * 16 + (lane & 15)) * BK + (lane >> 4) * 8];
#pragma unroll
    for (int g = 0; g < 4; ++g) {
      int o = (wn * 64 + g * 16 + (lane & 15)) * BK + (lane >> 4) * 8;
      fh[g] = *(const short8*)&Bh[o];
      fl[g] = *(const short8*)&Bl[o];
    }
#pragma unroll
    for (int f = 0; f < 4; ++f)
#pragma unroll
      for (int g = 0; g < 4; ++g) {
        acc[f][g] = __builtin_amdgcn_mfma_f32_16x16x32_bf16(af[f], fh[g], acc[f][g], 0, 0, 0);
        acc[f][g] = __builtin_amdgcn_mfma_f32_16x16x32_bf16(af[f], fl[g], acc[f][g], 0, 0, 0);
      }
  }
  int cr = lane >> 4, cc = lane & 15;
#pragma unroll
  for (int f = 0; f < 4; ++f) {
#pragma unroll
    for (int r = 0; r < 4; ++r) {
      int row = m0 + wm * 64 + f * 16 + cr * 4 + r;
      if (row >= M) continue;
      float sc = scale_store ? dinv[row] : 1.f;
#pragma unroll
      for (int g = 0; g < 4; ++g) {
        int col = n0 + wn * 64 + g * 16 + cc;
        float v = acc[f][g][r];
        if (mode) {
          v += bias[col];
          v = (mode == 1) ? (v > 0.f ? v : 0.01f * v) : (v > 0.f ? v : 0.f);
        }
        v *= sc;
        if (out_f32) ((float*)Cv)[(size_t)row * ldc + col] = v;
        else ((ushort_t*)Cv)[(size_t)row * ldc + col] = f2bf(v);
      }
    }
  }
}

// ---------------- driver ----------------

extern "C" void kernel_launch(void* const* d_in, const int* in_sizes, int n_in,
                              void* d_out, int out_size, void* d_ws, size_t ws_size,
                              hipStream_t stream) {
  const float* x  = (const float*)d_in[0];
  const int* ei   = (const int*)d_in[1];
  const float* W1 = (const float*)d_in[2];
  const float* b1 = (const float*)d_in[3];
  const float* W2 = (const float*)d_in[4];
  const float* b2 = (const float*)d_in[5];
  const float* W3 = (const float*)d_in[6];
  const float* b3 = (const float*)d_in[7];
  const float* W4 = (const float*)d_in[8];
  const float* b4 = (const float*)d_in[9];
  const float* Wl = (const float*)d_in[10];
  const float* bl = (const float*)d_in[11];

  char* p = (char*)d_ws;
  auto alloc = [&](size_t bytes) {
    char* r = p;
    p += (bytes + 255) & ~(size_t)255;
    return r;
  };
  int* cnt       = (int*)alloc((size_t)NNODES * 4);
  int* cursor    = (int*)alloc((size_t)NNODES * 4);
  int* row_ptr   = (int*)alloc((size_t)(NNODES + 1) * 4);
  float* dinv    = (float*)alloc((size_t)NNODES * 4);
  int* col_idx   = (int*)alloc((size_t)NEDGES * 4);
  int* tile_pref = (int*)alloc((size_t)NNODES * 4);
  int* tile_sum  = (int*)alloc(256 * 4);
  int* tile_base = (int*)alloc(256 * 4);
  ushort_t* W1h = (ushort_t*)alloc(49152 * 2); ushort_t* W1l = (ushort_t*)alloc(49152 * 2);
  ushort_t* W2h = (ushort_t*)alloc(49152 * 2); ushort_t* W2l = (ushort_t*)alloc(49152 * 2);
  ushort_t* W3h = (ushort_t*)alloc(98304 * 2); ushort_t* W3l = (ushort_t*)alloc(98304 * 2);
  ushort_t* W4h = (ushort_t*)alloc(98304 * 2); ushort_t* W4l = (ushort_t*)alloc(98304 * 2);
  ushort_t* Wlh = (ushort_t*)alloc(49152 * 2); ushort_t* Wll = (ushort_t*)alloc(49152 * 2);
  ushort_t* actA = (ushort_t*)alloc((size_t)NNODES * 384 * 2);
  ushort_t* actB = (ushort_t*)alloc((size_t)NNODES * 384 * 2);

  const int* src = ei;
  const int* dst = ei + NEDGES;

  hipMemsetAsync(cnt, 0, (size_t)NNODES * 4, stream);
  hist_kernel<<<(NEDGES + 255) / 256, 256, 0, stream>>>(dst, cnt);
  tile_scan_kernel<<<NTILES, 256, 0, stream>>>(cnt, tile_pref, tile_sum);
  sum_scan_kernel<<<1, 256, 0, stream>>>(tile_sum, tile_base);
  scan_write_kernel<<<NTILES, 256, 0, stream>>>(cnt, tile_pref, tile_base, row_ptr, cursor);
  dinv_kernel<<<(NNODES + 255) / 256, 256, 0, stream>>>(cnt, dinv);
  fill_kernel<<<(NEDGES + 255) / 256, 256, 0, stream>>>(src, dst, cursor, col_idx);

  wprep_kernel<<<(49152 + 255) / 256, 256, 0, stream>>>(W1, W1h, W1l, 384, 128);
  wprep_kernel<<<(49152 + 255) / 256, 256, 0, stream>>>(W2, W2h, W2l, 128, 384);
  wprep_kernel<<<(98304 + 255) / 256, 256, 0, stream>>>(W3, W3h, W3l, 384, 256);
  wprep_kernel<<<(98304 + 255) / 256, 256, 0, stream>>>(W4, W4h, W4l, 256, 384);
  wprep_kernel<<<(49152 + 255) / 256, 256, 0, stream>>>(Wl, Wlh, Wll, 384, 128);

  // x (f32) -> bf16 in actB
  cvt_kernel<<<(NNODES * 384 / 4 + 255) / 256, 256, 0, stream>>>(x, actB, NNODES * 384 / 4);

  dim3 blk(256);
  int gm = (NNODES + BM - 1) / BM;  // 391
  int nagg = NNODES / 4;            // 12500 blocks, one wave per node

  // L1 (384->128): gemm (pre-scaled store), agg(+b1, leaky, pre-scaled store)
  gemm_mfma<<<dim3(gm, 1), blk, 0, stream>>>(actB, W1h, W1l, actA, (const float*)0, dinv, NNODES, 384, 128, 0, 1, 0);
  agg_kernel<2><<<nagg, blk, 0, stream>>>(actA, actB, row_ptr, col_idx, dinv, b1, 1, 1);
  // L2 (128->384): agg (plain), gemm(+b2, leaky)
  agg_kernel<2><<<nagg, blk, 0, stream>>>(actB, actA, row_ptr, col_idx, dinv, (const float*)0, 0, 0);
  gemm_mfma<<<dim3(gm, 3), blk, 0, stream>>>(actA, W2h, W2l, actB, b2, dinv, NNODES, 128, 384, 1, 0, 0);
  // L3 (384->256): gemm (pre-scaled store), agg(+b3, leaky, pre-scaled store)
  gemm_mfma<<<dim3(gm, 2), blk, 0, stream>>>(actB, W3h, W3l, actA, (const float*)0, dinv, NNODES, 384, 256, 0, 1, 0);
  agg_kernel<4><<<nagg, blk, 0, stream>>>(actA, actB, row_ptr, col_idx, dinv, b3, 1, 1);
  // L4 (256->384): agg (plain), gemm(+b4, leaky)
  agg_kernel<4><<<nagg, blk, 0, stream>>>(actB, actA, row_ptr, col_idx, dinv, (const float*)0, 0, 0);
  gemm_mfma<<<dim3(gm, 3), blk, 0, stream>>>(actA, W4h, W4l, actB, b4, dinv, NNODES, 256, 384, 1, 0, 0);
  // final linear (384->128) + relu -> d_out (f32)
  gemm_mfma<<<dim3(gm, 1), blk, 0, stream>>>(actB, Wlh, Wll, d_out, bl, dinv, NNODES, 384, 128, 2, 0, 1);
}

// Round 7
// 769.282 us; speedup vs baseline: 1.4934x; 1.0390x over previous
//
#include <hip/hip_runtime.h>

#define NNODES 50000
#define NEDGES 800000
#define NTILES ((NNODES + 255) / 256)   // 196

typedef unsigned short ushort_t;
typedef __attribute__((ext_vector_type(8))) short short8;
typedef __attribute__((ext_vector_type(4))) float floatx4;

__device__ __forceinline__ float bf2f(unsigned short u) {
  union { unsigned int i; float f; } v; v.i = ((unsigned int)u) << 16; return v.f;
}
__device__ __forceinline__ unsigned short f2bf(float f) {
  union { float f; unsigned int i; } v; v.f = f;
  unsigned int r = v.i + 0x7fffu + ((v.i >> 16) & 1u);
  return (unsigned short)(r >> 16);
}

// ---------------- graph preprocessing ----------------

__global__ void hist_kernel(const int* dst, int* cnt) {
  int i = blockIdx.x * 256 + threadIdx.x;
  if (i < NEDGES) atomicAdd(&cnt[dst[i]], 1);
}

__global__ void dinv_kernel(const int* cnt, float* dinv) {
  int i = blockIdx.x * 256 + threadIdx.x;
  if (i < NNODES) dinv[i] = rsqrtf((float)(cnt[i] + 1));  // +1 self loop
}

// ---- device-wide exclusive scan of cnt[0..NNODES) in 3 tiny kernels ----

__global__ __launch_bounds__(256) void tile_scan_kernel(
    const int* __restrict__ cnt, int* __restrict__ tile_pref, int* __restrict__ tile_sum) {
  __shared__ int s[256];
  int b = blockIdx.x, t = threadIdx.x;
  int i = b * 256 + t;
  int v = (i < NNODES) ? cnt[i] : 0;
  s[t] = v;
  __syncthreads();
#pragma unroll
  for (int off = 1; off < 256; off <<= 1) {
    int x = (t >= off) ? s[t - off] : 0;
    __syncthreads();
    s[t] += x;
    __syncthreads();
  }
  if (i < NNODES) tile_pref[i] = s[t] - v;   // exclusive within tile
  if (t == 255) tile_sum[b] = s[255];
}

__global__ __launch_bounds__(256) void sum_scan_kernel(
    const int* __restrict__ tile_sum, int* __restrict__ tile_base) {
  __shared__ int s[256];
  int t = threadIdx.x;
  int v = (t < NTILES) ? tile_sum[t] : 0;
  s[t] = v;
  __syncthreads();
#pragma unroll
  for (int off = 1; off < 256; off <<= 1) {
    int x = (t >= off) ? s[t - off] : 0;
    __syncthreads();
    s[t] += x;
    __syncthreads();
  }
  if (t < NTILES) tile_base[t] = s[t] - v;   // exclusive across tiles
}

__global__ __launch_bounds__(256) void scan_write_kernel(
    const int* __restrict__ cnt, const int* __restrict__ tile_pref,
    const int* __restrict__ tile_base, int* __restrict__ row_ptr,
    int* __restrict__ cursor) {
  int b = blockIdx.x, t = threadIdx.x;
  int i = b * 256 + t;
  if (i < NNODES) {
    int base = tile_base[b] + tile_pref[i];
    row_ptr[i] = base;
    cursor[i] = base;
    if (i == NNODES - 1) row_ptr[NNODES] = base + cnt[i];
  }
}

__global__ void fill_kernel(const int* src, const int* dst, int* cursor, int* col_idx) {
  int i = blockIdx.x * 256 + threadIdx.x;
  if (i < NEDGES) {
    int p = atomicAdd(&cursor[dst[i]], 1);
    col_idx[p] = src[i];
  }
}

// ---------------- weight prep: transpose + split into bf16 hi/lo ----------
__global__ void wprep_kernel(const float* W, ushort_t* hi, ushort_t* lo, int K, int N) {
  int idx = blockIdx.x * 256 + threadIdx.x;
  if (idx < K * N) {
    int n = idx / K, k = idx - n * K;
    float w = W[(size_t)k * N + n];
    unsigned short h = f2bf(w);
    hi[idx] = h;
    lo[idx] = f2bf(w - bf2f(h));
  }
}

// ---------------- aggregation (CSR, one wave per node, bf16 act) ----------
// Inputs PRE-SCALED by source dinv. out[i] = act(dinv[i]*sum + bias)[*dinv[i]]
// mode 0: plain; 1: +bias leaky_relu(0.01)

template <int WPL>
__device__ __forceinline__ void load_row(const ushort_t* p, float* f) {
  if (WPL == 2) {
    unsigned int u = *(const unsigned int*)p;
    f[0] = bf2f((unsigned short)(u & 0xffff));
    f[1] = bf2f((unsigned short)(u >> 16));
  } else {
    uint2 u = *(const uint2*)p;
    f[0] = bf2f((unsigned short)(u.x & 0xffff));
    f[1] = bf2f((unsigned short)(u.x >> 16));
    f[2] = bf2f((unsigned short)(u.y & 0xffff));
    f[3] = bf2f((unsigned short)(u.y >> 16));
  }
}

template <int WPL>
__global__ __launch_bounds__(256) void agg_kernel(
    const ushort_t* __restrict__ in, ushort_t* __restrict__ out,
    const int* __restrict__ row_ptr, const int* __restrict__ col_idx,
    const float* __restrict__ dinv, const float* __restrict__ bias,
    int mode, int scale_store) {
  const int W = WPL * 64;
  int wid = blockIdx.x * 4 + (threadIdx.x >> 6);
  int lane = threadIdx.x & 63;
  int co = lane * WPL;
  const ushort_t* base = in + co;
  float acc[WPL];
  {
    float v[WPL];
    load_row<WPL>(base + (size_t)wid * W, v);
#pragma unroll
    for (int c = 0; c < WPL; ++c) acc[c] = v[c];
  }
  int e = row_ptr[wid], e1 = row_ptr[wid + 1];
  for (; e + 8 <= e1; e += 8) {
    int j[8];
#pragma unroll
    for (int q = 0; q < 8; ++q) j[q] = col_idx[e + q];
    float v[8][WPL];
#pragma unroll
    for (int q = 0; q < 8; ++q) load_row<WPL>(base + (size_t)j[q] * W, v[q]);
#pragma unroll
    for (int c = 0; c < WPL; ++c)
      acc[c] += ((v[0][c] + v[1][c]) + (v[2][c] + v[3][c])) +
                ((v[4][c] + v[5][c]) + (v[6][c] + v[7][c]));
  }
  for (; e + 2 <= e1; e += 2) {
    int j0 = col_idx[e], j1 = col_idx[e + 1];
    float v0[WPL], v1[WPL];
    load_row<WPL>(base + (size_t)j0 * W, v0);
    load_row<WPL>(base + (size_t)j1 * W, v1);
#pragma unroll
    for (int c = 0; c < WPL; ++c) acc[c] += v0[c] + v1[c];
  }
  if (e < e1) {
    int j = col_idx[e];
    float v[WPL];
    load_row<WPL>(base + (size_t)j * W, v);
#pragma unroll
    for (int c = 0; c < WPL; ++c) acc[c] += v[c];
  }
  float di = dinv[wid];
  unsigned short o[WPL];
  if (mode) {
    float bb[WPL];
    if constexpr (WPL == 2) {
      float2 b2 = *(const float2*)(bias + co); bb[0] = b2.x; bb[1] = b2.y;
    } else {
      float4 b4 = *(const float4*)(bias + co);
      bb[0] = b4.x; bb[1] = b4.y; bb[2] = b4.z; bb[3] = b4.w;
    }
    float sc = scale_store ? di : 1.f;
#pragma unroll
    for (int c = 0; c < WPL; ++c) {
      float v = acc[c] * di + bb[c];
      v = v > 0.f ? v : 0.01f * v;
      o[c] = f2bf(v * sc);
    }
  } else {
#pragma unroll
    for (int c = 0; c < WPL; ++c) o[c] = f2bf(acc[c] * di);
  }
  if constexpr (WPL == 2) {
    *(unsigned int*)(out + (size_t)wid * W + co) =
        (unsigned int)o[0] | ((unsigned int)o[1] << 16);
  } else {
    uint2 u;
    u.x = (unsigned int)o[0] | ((unsigned int)o[1] << 16);
    u.y = (unsigned int)o[2] | ((unsigned int)o[3] << 16);
    *(uint2*)(out + (size_t)wid * W + co) = u;
  }
}

// ---------------- MFMA GEMM: C = A[M,K] @ (Bhi+Blo)[N,K]^T ----------------
// TBM x 128 tile, BK=32, 4 waves (2x2), 16x16x32 bf16 MFMA, hi/lo split
// weights (f32-accurate). a_f32: A is f32, converted in-register while
// staging. mode 0: raw; 1: +bias leaky; 2: +bias relu. scale_store: *dinv[row].

#define BK 32

template <int TBM>
__global__ __launch_bounds__(256, 4) void gemm_mfma(
    const void* __restrict__ Av, const ushort_t* __restrict__ Bhi,
    const ushort_t* __restrict__ Blo, void* __restrict__ Cv,
    const float* __restrict__ bias, const float* __restrict__ dinv,
    int M, int K, int ldc, int mode, int scale_store, int out_f32, int a_f32) {
  constexpr int FR = TBM / 32;        // fragment rows per wave (wave = TBM/2 rows)
  constexpr int AIT = TBM / 64;       // A staging iterations
  __shared__ ushort_t As[TBM * BK];
  __shared__ ushort_t Bh[128 * BK];
  __shared__ ushort_t Bl[128 * BK];
  int tid = threadIdx.x;
  int lane = tid & 63, w = tid >> 6;
  int wm = w & 1, wn = w >> 1;
  int m0 = blockIdx.x * TBM, n0 = blockIdx.y * 128;
  floatx4 acc[FR][4] = {};
  int nkt = K / BK;
  for (int kt = 0; kt < nkt; ++kt) {
    int kb = kt * BK;
    uint4 va[AIT], vh[2], vl[2];
#pragma unroll
    for (int it = 0; it < AIT; ++it) {
      int s = it * 256 + tid;
      int row = s >> 2, ks = (s & 3) * 8;
      int gr = m0 + row; if (gr > M - 1) gr = M - 1;  // clamp loads; stores guarded
      if (a_f32) {
        const float* Af = (const float*)Av;
        float4 p0 = *(const float4*)(Af + (size_t)gr * K + kb + ks);
        float4 p1 = *(const float4*)(Af + (size_t)gr * K + kb + ks + 4);
        uint4 u;
        u.x = (unsigned int)f2bf(p0.x) | ((unsigned int)f2bf(p0.y) << 16);
        u.y = (unsigned int)f2bf(p0.z) | ((unsigned int)f2bf(p0.w) << 16);
        u.z = (unsigned int)f2bf(p1.x) | ((unsigned int)f2bf(p1.y) << 16);
        u.w = (unsigned int)f2bf(p1.z) | ((unsigned int)f2bf(p1.w) << 16);
        va[it] = u;
      } else {
        va[it] = *(const uint4*)((const ushort_t*)Av + (size_t)gr * K + kb + ks);
      }
    }
#pragma unroll
    for (int it = 0; it < 2; ++it) {
      int s = it * 256 + tid;
      int row = s >> 2, ks = (s & 3) * 8;
      vh[it] = *(const uint4*)(Bhi + (size_t)(n0 + row) * K + kb + ks);
      vl[it] = *(const uint4*)(Blo + (size_t)(n0 + row) * K + kb + ks);
    }
    __syncthreads();  // previous iteration's LDS reads complete
#pragma unroll
    for (int it = 0; it < AIT; ++it) {
      int s = it * 256 + tid;
      int row = s >> 2, ks = (s & 3) * 8;
      *(uint4*)&As[row * BK + ks] = va[it];
    }
#pragma unroll
    for (int it = 0; it < 2; ++it) {
      int s = it * 256 + tid;
      int row = s >> 2, ks = (s & 3) * 8;
      *(uint4*)&Bh[row * BK + ks] = vh[it];
      *(uint4*)&Bl[row * BK + ks] = vl[it];
    }
    __syncthreads();
    short8 af[FR], fh[4], fl[4];
#pragma unroll
    for (int f = 0; f < FR; ++f)
      af[f] = *(const short8*)&As[(wm * (TBM / 2) + f * 16 + (lane & 15)) * BK + (lane >> 4) * 8];
#pragma unroll
    for (int g = 0; g < 4; ++g) {
      int o = (wn * 64 + g * 16 + (lane & 15)) * BK + (lane >> 4) * 8;
      fh[g] = *(const short8*)&Bh[o];
      fl[g] = *(const short8*)&Bl[o];
    }
#pragma unroll
    for (int f = 0; f < FR; ++f)
#pragma unroll
      for (int g = 0; g < 4; ++g) {
        acc[f][g] = __builtin_amdgcn_mfma_f32_16x16x32_bf16(af[f], fh[g], acc[f][g], 0, 0, 0);
        acc[f][g] = __builtin_amdgcn_mfma_f32_16x16x32_bf16(af[f], fl[g], acc[f][g], 0, 0, 0);
      }
  }
  int cr = lane >> 4, cc = lane & 15;
#pragma unroll
  for (int f = 0; f < FR; ++f) {
#pragma unroll
    for (int r = 0; r < 4; ++r) {
      int row = m0 + wm * (TBM / 2) + f * 16 + cr * 4 + r;
      if (row >= M) continue;
      float sc = scale_store ? dinv[row] : 1.f;
#pragma unroll
      for (int g = 0; g < 4; ++g) {
        int col = n0 + wn * 64 + g * 16 + cc;
        float v = acc[f][g][r];
        if (mode) {
          v += bias[col];
          v = (mode == 1) ? (v > 0.f ? v : 0.01f * v) : (v > 0.f ? v : 0.f);
        }
        v *= sc;
        if (out_f32) ((float*)Cv)[(size_t)row * ldc + col] = v;
        else ((ushort_t*)Cv)[(size_t)row * ldc + col] = f2bf(v);
      }
    }
  }
}

// ---------------- driver ----------------

extern "C" void kernel_launch(void* const* d_in, const int* in_sizes, int n_in,
                              void* d_out, int out_size, void* d_ws, size_t ws_size,
                              hipStream_t stream) {
  const float* x  = (const float*)d_in[0];
  const int* ei   = (const int*)d_in[1];
  const float* W1 = (const float*)d_in[2];
  const float* b1 = (const float*)d_in[3];
  const float* W2 = (const float*)d_in[4];
  const float* b2 = (const float*)d_in[5];
  const float* W3 = (const float*)d_in[6];
  const float* b3 = (const float*)d_in[7];
  const float* W4 = (const float*)d_in[8];
  const float* b4 = (const float*)d_in[9];
  const float* Wl = (const float*)d_in[10];
  const float* bl = (const float*)d_in[11];

  char* p = (char*)d_ws;
  auto alloc = [&](size_t bytes) {
    char* r = p;
    p += (bytes + 255) & ~(size_t)255;
    return r;
  };
  int* cnt       = (int*)alloc((size_t)NNODES * 4);
  int* cursor    = (int*)alloc((size_t)NNODES * 4);
  int* row_ptr   = (int*)alloc((size_t)(NNODES + 1) * 4);
  float* dinv    = (float*)alloc((size_t)NNODES * 4);
  int* col_idx   = (int*)alloc((size_t)NEDGES * 4);
  int* tile_pref = (int*)alloc((size_t)NNODES * 4);
  int* tile_sum  = (int*)alloc(256 * 4);
  int* tile_base = (int*)alloc(256 * 4);
  ushort_t* W1h = (ushort_t*)alloc(49152 * 2); ushort_t* W1l = (ushort_t*)alloc(49152 * 2);
  ushort_t* W2h = (ushort_t*)alloc(49152 * 2); ushort_t* W2l = (ushort_t*)alloc(49152 * 2);
  ushort_t* W3h = (ushort_t*)alloc(98304 * 2); ushort_t* W3l = (ushort_t*)alloc(98304 * 2);
  ushort_t* W4h = (ushort_t*)alloc(98304 * 2); ushort_t* W4l = (ushort_t*)alloc(98304 * 2);
  ushort_t* Wlh = (ushort_t*)alloc(49152 * 2); ushort_t* Wll = (ushort_t*)alloc(49152 * 2);
  ushort_t* actA = (ushort_t*)alloc((size_t)NNODES * 384 * 2);
  ushort_t* actB = (ushort_t*)alloc((size_t)NNODES * 384 * 2);

  const int* src = ei;
  const int* dst = ei + NEDGES;

  hipMemsetAsync(cnt, 0, (size_t)NNODES * 4, stream);
  hist_kernel<<<(NEDGES + 255) / 256, 256, 0, stream>>>(dst, cnt);
  tile_scan_kernel<<<NTILES, 256, 0, stream>>>(cnt, tile_pref, tile_sum);
  sum_scan_kernel<<<1, 256, 0, stream>>>(tile_sum, tile_base);
  scan_write_kernel<<<NTILES, 256, 0, stream>>>(cnt, tile_pref, tile_base, row_ptr, cursor);
  dinv_kernel<<<(NNODES + 255) / 256, 256, 0, stream>>>(cnt, dinv);
  fill_kernel<<<(NEDGES + 255) / 256, 256, 0, stream>>>(src, dst, cursor, col_idx);

  wprep_kernel<<<(49152 + 255) / 256, 256, 0, stream>>>(W1, W1h, W1l, 384, 128);
  wprep_kernel<<<(49152 + 255) / 256, 256, 0, stream>>>(W2, W2h, W2l, 128, 384);
  wprep_kernel<<<(98304 + 255) / 256, 256, 0, stream>>>(W3, W3h, W3l, 384, 256);
  wprep_kernel<<<(98304 + 255) / 256, 256, 0, stream>>>(W4, W4h, W4l, 256, 384);
  wprep_kernel<<<(49152 + 255) / 256, 256, 0, stream>>>(Wl, Wlh, Wll, 384, 128);

  dim3 blk(256);
  int gm64  = (NNODES + 63) / 64;    // 782 blocks for TBM=64
  int gm128 = (NNODES + 127) / 128;  // 391 blocks for TBM=128
  int nagg = NNODES / 4;             // 12500 blocks, one wave per node

  // L1 (384->128): gemm reads x f32 directly (pre-scaled store), agg(+b1, leaky, pre-scaled)
  gemm_mfma<64><<<dim3(gm64, 1), blk, 0, stream>>>(x, W1h, W1l, actA, (const float*)0, dinv, NNODES, 384, 128, 0, 1, 0, 1);
  agg_kernel<2><<<nagg, blk, 0, stream>>>(actA, actB, row_ptr, col_idx, dinv, b1, 1, 1);
  // L2 (128->384): agg (plain), gemm(+b2, leaky)
  agg_kernel<2><<<nagg, blk, 0, stream>>>(actB, actA, row_ptr, col_idx, dinv, (const float*)0, 0, 0);
  gemm_mfma<128><<<dim3(gm128, 3), blk, 0, stream>>>(actA, W2h, W2l, actB, b2, dinv, NNODES, 128, 384, 1, 0, 0, 0);
  // L3 (384->256): gemm (pre-scaled store), agg(+b3, leaky, pre-scaled store)
  gemm_mfma<128><<<dim3(gm128, 2), blk, 0, stream>>>(actB, W3h, W3l, actA, (const float*)0, dinv, NNODES, 384, 256, 0, 1, 0, 0);
  agg_kernel<4><<<nagg, blk, 0, stream>>>(actA, actB, row_ptr, col_idx, dinv, b3, 1, 1);
  // L4 (256->384): agg (plain), gemm(+b4, leaky)
  agg_kernel<4><<<nagg, blk, 0, stream>>>(actB, actA, row_ptr, col_idx, dinv, (const float*)0, 0, 0);
  gemm_mfma<128><<<dim3(gm128, 3), blk, 0, stream>>>(actA, W4h, W4l, actB, b4, dinv, NNODES, 256, 384, 1, 0, 0, 0);
  // final linear (384->128) + relu -> d_out (f32)
  gemm_mfma<64><<<dim3(gm64, 1), blk, 0, stream>>>(actB, Wlh, Wll, d_out, bl, dinv, NNODES, 384, 128, 2, 0, 1, 0);
}

// Round 8
// 612.894 us; speedup vs baseline: 1.8744x; 1.2552x over previous
//
#include <hip/hip_runtime.h>

#define NNODES 50000
#define NEDGES 800000
#define NTILES ((NNODES + 255) / 256)   // 196

typedef unsigned short ushort_t;
typedef __attribute__((ext_vector_type(8))) short short8;
typedef __attribute__((ext_vector_type(4))) float floatx4;

__device__ __forceinline__ float bf2f(unsigned short u) {
  union { unsigned int i; float f; } v; v.i = ((unsigned int)u) << 16; return v.f;
}
__device__ __forceinline__ unsigned short f2bf(float f) {
  union { float f; unsigned int i; } v; v.f = f;
  unsigned int r = v.i + 0x7fffu + ((v.i >> 16) & 1u);
  return (unsigned short)(r >> 16);
}

__device__ __forceinline__ void gload_lds16(const void* g, void* l) {
  __builtin_amdgcn_global_load_lds(
      (const __attribute__((address_space(1))) unsigned int*)g,
      (__attribute__((address_space(3))) unsigned int*)l, 16, 0, 0);
}

// ---------------- graph preprocessing ----------------

__global__ void hist_kernel(const int* dst, int* cnt) {
  int i = blockIdx.x * 256 + threadIdx.x;
  if (i < NEDGES) atomicAdd(&cnt[dst[i]], 1);
}

__global__ void dinv_kernel(const int* cnt, float* dinv) {
  int i = blockIdx.x * 256 + threadIdx.x;
  if (i < NNODES) dinv[i] = rsqrtf((float)(cnt[i] + 1));  // +1 self loop
}

// ---- device-wide exclusive scan of cnt[0..NNODES) in 3 tiny kernels ----

__global__ __launch_bounds__(256) void tile_scan_kernel(
    const int* __restrict__ cnt, int* __restrict__ tile_pref, int* __restrict__ tile_sum) {
  __shared__ int s[256];
  int b = blockIdx.x, t = threadIdx.x;
  int i = b * 256 + t;
  int v = (i < NNODES) ? cnt[i] : 0;
  s[t] = v;
  __syncthreads();
#pragma unroll
  for (int off = 1; off < 256; off <<= 1) {
    int x = (t >= off) ? s[t - off] : 0;
    __syncthreads();
    s[t] += x;
    __syncthreads();
  }
  if (i < NNODES) tile_pref[i] = s[t] - v;   // exclusive within tile
  if (t == 255) tile_sum[b] = s[255];
}

__global__ __launch_bounds__(256) void sum_scan_kernel(
    const int* __restrict__ tile_sum, int* __restrict__ tile_base) {
  __shared__ int s[256];
  int t = threadIdx.x;
  int v = (t < NTILES) ? tile_sum[t] : 0;
  s[t] = v;
  __syncthreads();
#pragma unroll
  for (int off = 1; off < 256; off <<= 1) {
    int x = (t >= off) ? s[t - off] : 0;
    __syncthreads();
    s[t] += x;
    __syncthreads();
  }
  if (t < NTILES) tile_base[t] = s[t] - v;   // exclusive across tiles
}

__global__ __launch_bounds__(256) void scan_write_kernel(
    const int* __restrict__ cnt, const int* __restrict__ tile_pref,
    const int* __restrict__ tile_base, int* __restrict__ row_ptr,
    int* __restrict__ cursor) {
  int b = blockIdx.x, t = threadIdx.x;
  int i = b * 256 + t;
  if (i < NNODES) {
    int base = tile_base[b] + tile_pref[i];
    row_ptr[i] = base;
    cursor[i] = base;
    if (i == NNODES - 1) row_ptr[NNODES] = base + cnt[i];
  }
}

__global__ void fill_kernel(const int* src, const int* dst, int* cursor, int* col_idx) {
  int i = blockIdx.x * 256 + threadIdx.x;
  if (i < NEDGES) {
    int p = atomicAdd(&cursor[dst[i]], 1);
    col_idx[p] = src[i];
  }
}

// ---------------- weight prep: transpose + split into bf16 hi/lo ----------
__global__ void wprep_kernel(const float* W, ushort_t* hi, ushort_t* lo, int K, int N) {
  int idx = blockIdx.x * 256 + threadIdx.x;
  if (idx < K * N) {
    int n = idx / K, k = idx - n * K;
    float w = W[(size_t)k * N + n];
    unsigned short h = f2bf(w);
    hi[idx] = h;
    lo[idx] = f2bf(w - bf2f(h));
  }
}

// ---------------- aggregation (CSR, one wave per node, bf16 act) ----------
// Inputs PRE-SCALED by source dinv. out[i] = act(dinv[i]*sum + bias)[*dinv[i]]
// mode 0: plain; 1: +bias leaky_relu(0.01)

template <int WPL>
__device__ __forceinline__ void load_row(const ushort_t* p, float* f) {
  if (WPL == 2) {
    unsigned int u = *(const unsigned int*)p;
    f[0] = bf2f((unsigned short)(u & 0xffff));
    f[1] = bf2f((unsigned short)(u >> 16));
  } else {
    uint2 u = *(const uint2*)p;
    f[0] = bf2f((unsigned short)(u.x & 0xffff));
    f[1] = bf2f((unsigned short)(u.x >> 16));
    f[2] = bf2f((unsigned short)(u.y & 0xffff));
    f[3] = bf2f((unsigned short)(u.y >> 16));
  }
}

template <int WPL>
__global__ __launch_bounds__(256) void agg_kernel(
    const ushort_t* __restrict__ in, ushort_t* __restrict__ out,
    const int* __restrict__ row_ptr, const int* __restrict__ col_idx,
    const float* __restrict__ dinv, const float* __restrict__ bias,
    int mode, int scale_store) {
  const int W = WPL * 64;
  int wid = blockIdx.x * 4 + (threadIdx.x >> 6);
  int lane = threadIdx.x & 63;
  int co = lane * WPL;
  const ushort_t* base = in + co;
  float acc[WPL];
  {
    float v[WPL];
    load_row<WPL>(base + (size_t)wid * W, v);
#pragma unroll
    for (int c = 0; c < WPL; ++c) acc[c] = v[c];
  }
  int e = row_ptr[wid], e1 = row_ptr[wid + 1];
  for (; e + 16 <= e1; e += 16) {
    int j[16];
#pragma unroll
    for (int q = 0; q < 16; ++q) j[q] = col_idx[e + q];
    float v[16][WPL];
#pragma unroll
    for (int q = 0; q < 16; ++q) load_row<WPL>(base + (size_t)j[q] * W, v[q]);
#pragma unroll
    for (int c = 0; c < WPL; ++c) {
      float s0 = (v[0][c] + v[1][c]) + (v[2][c] + v[3][c]);
      float s1 = (v[4][c] + v[5][c]) + (v[6][c] + v[7][c]);
      float s2 = (v[8][c] + v[9][c]) + (v[10][c] + v[11][c]);
      float s3 = (v[12][c] + v[13][c]) + (v[14][c] + v[15][c]);
      acc[c] += (s0 + s1) + (s2 + s3);
    }
  }
  for (; e + 4 <= e1; e += 4) {
    int j0 = col_idx[e], j1 = col_idx[e + 1], j2 = col_idx[e + 2], j3 = col_idx[e + 3];
    float v0[WPL], v1[WPL], v2[WPL], v3[WPL];
    load_row<WPL>(base + (size_t)j0 * W, v0);
    load_row<WPL>(base + (size_t)j1 * W, v1);
    load_row<WPL>(base + (size_t)j2 * W, v2);
    load_row<WPL>(base + (size_t)j3 * W, v3);
#pragma unroll
    for (int c = 0; c < WPL; ++c) acc[c] += (v0[c] + v1[c]) + (v2[c] + v3[c]);
  }
  for (; e < e1; ++e) {
    int j = col_idx[e];
    float v[WPL];
    load_row<WPL>(base + (size_t)j * W, v);
#pragma unroll
    for (int c = 0; c < WPL; ++c) acc[c] += v[c];
  }
  float di = dinv[wid];
  unsigned short o[WPL];
  if (mode) {
    float bb[WPL];
    if constexpr (WPL == 2) {
      float2 b2 = *(const float2*)(bias + co); bb[0] = b2.x; bb[1] = b2.y;
    } else {
      float4 b4 = *(const float4*)(bias + co);
      bb[0] = b4.x; bb[1] = b4.y; bb[2] = b4.z; bb[3] = b4.w;
    }
    float sc = scale_store ? di : 1.f;
#pragma unroll
    for (int c = 0; c < WPL; ++c) {
      float v = acc[c] * di + bb[c];
      v = v > 0.f ? v : 0.01f * v;
      o[c] = f2bf(v * sc);
    }
  } else {
#pragma unroll
    for (int c = 0; c < WPL; ++c) o[c] = f2bf(acc[c] * di);
  }
  if constexpr (WPL == 2) {
    *(unsigned int*)(out + (size_t)wid * W + co) =
        (unsigned int)o[0] | ((unsigned int)o[1] << 16);
  } else {
    uint2 u;
    u.x = (unsigned int)o[0] | ((unsigned int)o[1] << 16);
    u.y = (unsigned int)o[2] | ((unsigned int)o[3] << 16);
    *(uint2*)(out + (size_t)wid * W + co) = u;
  }
}

// ---------------- MFMA GEMM: C = A[M,K] @ (Bhi+Blo)[N,K]^T ----------------
// TBM x TBN tile, BK=32, 4 waves (2x2), 16x16x32 bf16 MFMA, hi/lo split
// weights (f32-accurate). Staging via global_load_lds (16B) for bf16 A/B;
// a_f32 path converts f32->bf16 in-register for A. mode 0: raw; 1: +bias
// leaky; 2: +bias relu. scale_store: *dinv[row]. out_f32: f32 C.

#define BK 32

template <int TBM, int TBN>
__global__ __launch_bounds__(256, TBM == 64 ? 6 : 4) void gemm_mfma(
    const void* __restrict__ Av, const ushort_t* __restrict__ Bhi,
    const ushort_t* __restrict__ Blo, void* __restrict__ Cv,
    const float* __restrict__ bias, const float* __restrict__ dinv,
    int M, int K, int ldc, int mode, int scale_store, int out_f32, int a_f32) {
  constexpr int FR = TBM / 32;        // A fragments per wave
  constexpr int FG = TBN / 32;        // B fragments per wave
  constexpr int AIT = TBM / 64;       // A staging iterations (256 thr, 16B each)
  constexpr int BIT = TBN / 64;       // B staging iterations
  __shared__ ushort_t As[TBM * BK];
  __shared__ ushort_t Bh[TBN * BK];
  __shared__ ushort_t Bl[TBN * BK];
  int tid = threadIdx.x;
  int lane = tid & 63, w = tid >> 6;
  int wm = w & 1, wn = w >> 1;
  int m0 = blockIdx.x * TBM, n0 = blockIdx.y * TBN;
  floatx4 acc[FR][FG] = {};
  int nkt = K / BK;
  for (int kt = 0; kt < nkt; ++kt) {
    int kb = kt * BK;
    uint4 va[AIT];
    if (a_f32) {
      const float* Af = (const float*)Av;
#pragma unroll
      for (int it = 0; it < AIT; ++it) {
        int s = it * 256 + tid;
        int row = s >> 2, ks = (s & 3) * 8;
        int gr = m0 + row; if (gr > M - 1) gr = M - 1;
        float4 p0 = *(const float4*)(Af + (size_t)gr * K + kb + ks);
        float4 p1 = *(const float4*)(Af + (size_t)gr * K + kb + ks + 4);
        uint4 u;
        u.x = (unsigned int)f2bf(p0.x) | ((unsigned int)f2bf(p0.y) << 16);
        u.y = (unsigned int)f2bf(p0.z) | ((unsigned int)f2bf(p0.w) << 16);
        u.z = (unsigned int)f2bf(p1.x) | ((unsigned int)f2bf(p1.y) << 16);
        u.w = (unsigned int)f2bf(p1.z) | ((unsigned int)f2bf(p1.w) << 16);
        va[it] = u;
      }
    }
    __syncthreads();  // previous iteration's LDS reads complete
    if (a_f32) {
#pragma unroll
      for (int it = 0; it < AIT; ++it) {
        int s = it * 256 + tid;
        *(uint4*)&As[s * 8] = va[it];
      }
    } else {
#pragma unroll
      for (int it = 0; it < AIT; ++it) {
        int s = it * 256 + tid;
        int row = s >> 2, ks = (s & 3) * 8;
        int gr = m0 + row; if (gr > M - 1) gr = M - 1;  // clamp; stores guarded
        gload_lds16((const ushort_t*)Av + (size_t)gr * K + kb + ks,
                    As + (size_t)(it * 256 + w * 64) * 8);
      }
    }
#pragma unroll
    for (int it = 0; it < BIT; ++it) {
      int s = it * 256 + tid;
      int row = s >> 2, ks = (s & 3) * 8;
      gload_lds16(Bhi + (size_t)(n0 + row) * K + kb + ks,
                  Bh + (size_t)(it * 256 + w * 64) * 8);
      gload_lds16(Blo + (size_t)(n0 + row) * K + kb + ks,
                  Bl + (size_t)(it * 256 + w * 64) * 8);
    }
    __syncthreads();  // drains vmcnt (incl. LDS-DMA) and lgkm
    short8 af[FR], fh[FG], fl[FG];
#pragma unroll
    for (int f = 0; f < FR; ++f)
      af[f] = *(const short8*)&As[(wm * (TBM / 2) + f * 16 + (lane & 15)) * BK + (lane >> 4) * 8];
#pragma unroll
    for (int g = 0; g < FG; ++g) {
      int o = (wn * (TBN / 2) + g * 16 + (lane & 15)) * BK + (lane >> 4) * 8;
      fh[g] = *(const short8*)&Bh[o];
      fl[g] = *(const short8*)&Bl[o];
    }
#pragma unroll
    for (int f = 0; f < FR; ++f)
#pragma unroll
      for (int g = 0; g < FG; ++g) {
        acc[f][g] = __builtin_amdgcn_mfma_f32_16x16x32_bf16(af[f], fh[g], acc[f][g], 0, 0, 0);
        acc[f][g] = __builtin_amdgcn_mfma_f32_16x16x32_bf16(af[f], fl[g], acc[f][g], 0, 0, 0);
      }
  }
  int cr = lane >> 4, cc = lane & 15;
#pragma unroll
  for (int f = 0; f < FR; ++f) {
#pragma unroll
    for (int r = 0; r < 4; ++r) {
      int row = m0 + wm * (TBM / 2) + f * 16 + cr * 4 + r;
      if (row >= M) continue;
      float sc = scale_store ? dinv[row] : 1.f;
#pragma unroll
      for (int g = 0; g < FG; ++g) {
        int col = n0 + wn * (TBN / 2) + g * 16 + cc;
        float v = acc[f][g][r];
        if (mode) {
          v += bias[col];
          v = (mode == 1) ? (v > 0.f ? v : 0.01f * v) : (v > 0.f ? v : 0.f);
        }
        v *= sc;
        if (out_f32) ((float*)Cv)[(size_t)row * ldc + col] = v;
        else ((ushort_t*)Cv)[(size_t)row * ldc + col] = f2bf(v);
      }
    }
  }
}

// ---------------- driver ----------------

extern "C" void kernel_launch(void* const* d_in, const int* in_sizes, int n_in,
                              void* d_out, int out_size, void* d_ws, size_t ws_size,
                              hipStream_t stream) {
  const float* x  = (const float*)d_in[0];
  const int* ei   = (const int*)d_in[1];
  const float* W1 = (const float*)d_in[2];
  const float* b1 = (const float*)d_in[3];
  const float* W2 = (const float*)d_in[4];
  const float* b2 = (const float*)d_in[5];
  const float* W3 = (const float*)d_in[6];
  const float* b3 = (const float*)d_in[7];
  const float* W4 = (const float*)d_in[8];
  const float* b4 = (const float*)d_in[9];
  const float* Wl = (const float*)d_in[10];
  const float* bl = (const float*)d_in[11];

  char* p = (char*)d_ws;
  auto alloc = [&](size_t bytes) {
    char* r = p;
    p += (bytes + 255) & ~(size_t)255;
    return r;
  };
  int* cnt       = (int*)alloc((size_t)NNODES * 4);
  int* cursor    = (int*)alloc((size_t)NNODES * 4);
  int* row_ptr   = (int*)alloc((size_t)(NNODES + 1) * 4);
  float* dinv    = (float*)alloc((size_t)NNODES * 4);
  int* col_idx   = (int*)alloc((size_t)NEDGES * 4);
  int* tile_pref = (int*)alloc((size_t)NNODES * 4);
  int* tile_sum  = (int*)alloc(256 * 4);
  int* tile_base = (int*)alloc(256 * 4);
  ushort_t* W1h = (ushort_t*)alloc(49152 * 2); ushort_t* W1l = (ushort_t*)alloc(49152 * 2);
  ushort_t* W2h = (ushort_t*)alloc(49152 * 2); ushort_t* W2l = (ushort_t*)alloc(49152 * 2);
  ushort_t* W3h = (ushort_t*)alloc(98304 * 2); ushort_t* W3l = (ushort_t*)alloc(98304 * 2);
  ushort_t* W4h = (ushort_t*)alloc(98304 * 2); ushort_t* W4l = (ushort_t*)alloc(98304 * 2);
  ushort_t* Wlh = (ushort_t*)alloc(49152 * 2); ushort_t* Wll = (ushort_t*)alloc(49152 * 2);
  ushort_t* actA = (ushort_t*)alloc((size_t)NNODES * 384 * 2);
  ushort_t* actB = (ushort_t*)alloc((size_t)NNODES * 384 * 2);

  const int* src = ei;
  const int* dst = ei + NEDGES;

  hipMemsetAsync(cnt, 0, (size_t)NNODES * 4, stream);
  hist_kernel<<<(NEDGES + 255) / 256, 256, 0, stream>>>(dst, cnt);
  tile_scan_kernel<<<NTILES, 256, 0, stream>>>(cnt, tile_pref, tile_sum);
  sum_scan_kernel<<<1, 256, 0, stream>>>(tile_sum, tile_base);
  scan_write_kernel<<<NTILES, 256, 0, stream>>>(cnt, tile_pref, tile_base, row_ptr, cursor);
  dinv_kernel<<<(NNODES + 255) / 256, 256, 0, stream>>>(cnt, dinv);
  fill_kernel<<<(NEDGES + 255) / 256, 256, 0, stream>>>(src, dst, cursor, col_idx);

  wprep_kernel<<<(49152 + 255) / 256, 256, 0, stream>>>(W1, W1h, W1l, 384, 128);
  wprep_kernel<<<(49152 + 255) / 256, 256, 0, stream>>>(W2, W2h, W2l, 128, 384);
  wprep_kernel<<<(98304 + 255) / 256, 256, 0, stream>>>(W3, W3h, W3l, 384, 256);
  wprep_kernel<<<(98304 + 255) / 256, 256, 0, stream>>>(W4, W4h, W4l, 256, 384);
  wprep_kernel<<<(49152 + 255) / 256, 256, 0, stream>>>(Wl, Wlh, Wll, 384, 128);

  dim3 blk(256);
  int gm64  = (NNODES + 63) / 64;    // 782
  int gm128 = (NNODES + 127) / 128;  // 391
  int nagg = NNODES / 4;             // 12500 blocks, one wave per node

  // L1 (384->128): gemm reads x f32 directly (pre-scaled store), agg(+b1, leaky, pre-scaled)
  gemm_mfma<64, 64><<<dim3(gm64, 2), blk, 0, stream>>>(x, W1h, W1l, actA, (const float*)0, dinv, NNODES, 384, 128, 0, 1, 0, 1);
  agg_kernel<2><<<nagg, blk, 0, stream>>>(actA, actB, row_ptr, col_idx, dinv, b1, 1, 1);
  // L2 (128->384): agg (plain), gemm(+b2, leaky)
  agg_kernel<2><<<nagg, blk, 0, stream>>>(actB, actA, row_ptr, col_idx, dinv, (const float*)0, 0, 0);
  gemm_mfma<128, 128><<<dim3(gm128, 3), blk, 0, stream>>>(actA, W2h, W2l, actB, b2, dinv, NNODES, 128, 384, 1, 0, 0, 0);
  // L3 (384->256): gemm (pre-scaled store), agg(+b3, leaky, pre-scaled store)
  gemm_mfma<128, 128><<<dim3(gm128, 2), blk, 0, stream>>>(actB, W3h, W3l, actA, (const float*)0, dinv, NNODES, 384, 256, 0, 1, 0, 0);
  agg_kernel<4><<<nagg, blk, 0, stream>>>(actA, actB, row_ptr, col_idx, dinv, b3, 1, 1);
  // L4 (256->384): agg (plain), gemm(+b4, leaky)
  agg_kernel<4><<<nagg, blk, 0, stream>>>(actB, actA, row_ptr, col_idx, dinv, (const float*)0, 0, 0);
  gemm_mfma<128, 128><<<dim3(gm128, 3), blk, 0, stream>>>(actA, W4h, W4l, actB, b4, dinv, NNODES, 256, 384, 1, 0, 0, 0);
  // final linear (384->128) + relu -> d_out (f32)
  gemm_mfma<64, 64><<<dim3(gm64, 2), blk, 0, stream>>>(actB, Wlh, Wll, d_out, bl, dinv, NNODES, 384, 128, 2, 0, 1, 0);
}